// Round 1
// baseline (200.282 us; speedup 1.0000x reference)
//
#include <hip/hip_runtime.h>

#define NSTREAMS 4
#define DIM 256
#define BM 16
#define NTHREADS 512
#define TILES 8

typedef __attribute__((ext_vector_type(8))) short short8;
typedef __attribute__((ext_vector_type(4))) float f32x4;

// f32 -> bf16 round-to-nearest-even (scalar, bit-twiddle)
static __device__ __forceinline__ short f2bf(float x) {
    union { float f; unsigned int u; } c; c.f = x;
    unsigned int u = c.u;
    unsigned int lsb = (u >> 16) & 1u;
    u += 0x7fffu + lsb;
    return (short)(u >> 16);
}
// f32x4 -> packed bf16x4 via HW v_cvt_pk_bf16_f32 (RNE, bit-identical to f2bf)
static __device__ __forceinline__ int2 f2bf4(float4 v) {
    unsigned int lo, hi;
    asm("v_cvt_pk_bf16_f32 %0, %1, %2" : "=v"(lo) : "v"(v.x), "v"(v.y));
    asm("v_cvt_pk_bf16_f32 %0, %1, %2" : "=v"(hi) : "v"(v.z), "v"(v.w));
    int2 r; r.x = (int)lo; r.y = (int)hi;
    return r;
}

// Block barrier that drains LDS ops only — does NOT drain vmcnt, so global
// loads issued before it stay in flight across the barrier (T4 discipline).
// All global loads in this kernel land in registers, so LDS visibility
// (lgkmcnt) is the only cross-wave hazard at these barriers.
static __device__ __forceinline__ void barrier_lgkm() {
    asm volatile("s_waitcnt lgkmcnt(0)\n\ts_barrier" ::: "memory");
}

// Sinkhorn (4x4, 10 iters, tau=0.05) + two softmaxes.
// h_out[0..15]=h_res (row-major s,t), [16..19]=h_pre, [20..23]=h_post
static __device__ void compute_h(const float* __restrict__ hres_l,
                                 const float* __restrict__ hpre_l,
                                 const float* __restrict__ hpost_l,
                                 float* h_out) {
    const float inv_tau = 1.0f / 0.05f;
    float z[4][4];
    for (int i = 0; i < 4; ++i)
        for (int j = 0; j < 4; ++j)
            z[i][j] = hres_l[i * 4 + j] * inv_tau;
    float u[4] = {0.f, 0.f, 0.f, 0.f};
    float v[4] = {0.f, 0.f, 0.f, 0.f};
    const float logm = -logf(4.0f);
    for (int it = 0; it < 10; ++it) {
        for (int i = 0; i < 4; ++i) {
            float m = -1e30f;
            for (int j = 0; j < 4; ++j) m = fmaxf(m, z[i][j] + v[j]);
            float ss = 0.f;
            for (int j = 0; j < 4; ++j) ss += expf(z[i][j] + v[j] - m);
            u[i] = logm - (m + logf(ss));
        }
        for (int j = 0; j < 4; ++j) {
            float m = -1e30f;
            for (int i = 0; i < 4; ++i) m = fmaxf(m, z[i][j] + u[i]);
            float ss = 0.f;
            for (int i = 0; i < 4; ++i) ss += expf(z[i][j] + u[i] - m);
            v[j] = logm - (m + logf(ss));
        }
    }
    for (int i = 0; i < 4; ++i)
        for (int j = 0; j < 4; ++j)
            h_out[i * 4 + j] = expf(z[i][j] + u[i] + v[j]) * 4.0f;
    {
        float m = fmaxf(fmaxf(hpre_l[0], hpre_l[1]), fmaxf(hpre_l[2], hpre_l[3]));
        float e0 = expf(hpre_l[0] - m), e1 = expf(hpre_l[1] - m);
        float e2 = expf(hpre_l[2] - m), e3 = expf(hpre_l[3] - m);
        float ss = e0 + e1 + e2 + e3;
        h_out[16] = e0 / ss; h_out[17] = e1 / ss; h_out[18] = e2 / ss; h_out[19] = e3 / ss;
    }
    {
        float m = fmaxf(fmaxf(hpost_l[0], hpost_l[1]), fmaxf(hpost_l[2], hpost_l[3]));
        float e0 = expf(hpost_l[0] - m), e1 = expf(hpost_l[1] - m);
        float e2 = expf(hpost_l[2] - m), e3 = expf(hpost_l[3] - m);
        float ss = e0 + e1 + e2 + e3;
        h_out[20] = e0 / ss; h_out[21] = e1 / ss; h_out[22] = e2 / ss; h_out[23] = e3 / ss;
    }
}

__global__ void prep_h_kernel(const float* __restrict__ hres_l,
                              const float* __restrict__ hpre_l,
                              const float* __restrict__ hpost_l,
                              float* __restrict__ ws) {
    if (threadIdx.x == 0) compute_h(hres_l, hpre_l, hpost_l, ws);
}

// Convert W to bf16 into ws (RNE) + compute h in block 0 (disjoint ws region).
__global__ __launch_bounds__(256) void prep_wh_kernel(const float* __restrict__ Wb,
                                                      short* __restrict__ wbf,
                                                      const float* __restrict__ hres_l,
                                                      const float* __restrict__ hpre_l,
                                                      const float* __restrict__ hpost_l,
                                                      float* __restrict__ ws_h) {
    int idx = blockIdx.x * 256 + threadIdx.x;   // 16384 float4 tasks
    float4 v = reinterpret_cast<const float4*>(Wb)[idx];
    reinterpret_cast<int2*>(wbf)[idx] = f2bf4(v);
    if (blockIdx.x == 0 && threadIdx.x == 0)
        compute_h(hres_l, hpre_l, hpost_l, ws_h);
}

template <bool USE_WSW>
__global__ __launch_bounds__(NTHREADS, 4) void fused_kernel(
    const float* __restrict__ res,
    const float* __restrict__ Wb,
    const short* __restrict__ wbf,    // bf16 W in ws (when USE_WSW)
    const float* __restrict__ hptr,   // 24 floats in ws, or nullptr
    const float* __restrict__ hres_l,
    const float* __restrict__ hpre_l,
    const float* __restrict__ hpost_l,
    float* __restrict__ out)
{
    // res_lds removed: each thread's residual slice is a pure register
    // pass-through (same thread wrote & read it) — keep it in f32 regs.
    // bo_lds is f32 now (no bf16 round-trip); +4 pad -> 2-way conflicts (free).
    __shared__ __align__(16) short bi_lds[BM][DIM + 8];   // 8.25 KB
    __shared__ __align__(16) float bo_lds[BM][DIM + 4];   // 16.6 KB
    __shared__ float h_sh[24];

    const int t  = threadIdx.x;
    const int d4 = t & 63;
    const int r0 = t >> 6;    // 0..7; this thread owns rows r0 and r0+8
    const int w  = t >> 6;    // GEMM wave id 0..7
    const int l  = t & 63;
    const int lr = l & 15;    // A row / B col within 16-tile
    const int lk = l >> 4;    // k-block 0..3

    if (hptr) {
        if (t < 24) h_sh[t] = hptr[t];
    } else if (t == 0) {
        compute_h(hres_l, hpre_l, hpost_l, h_sh);
    }
    barrier_lgkm();

    const float hp0 = h_sh[16], hp1 = h_sh[17], hp2 = h_sh[18], hp3 = h_sh[19];
    float hres[4][4];
    #pragma unroll
    for (int s = 0; s < 4; ++s)
        #pragma unroll
        for (int tt = 0; tt < 4; ++tt)
            hres[s][tt] = h_sh[s * 4 + tt];
    float hq[4] = {h_sh[20], h_sh[21], h_sh[22], h_sh[23]};

    const long tile0 = (long)blockIdx.x * TILES;

    // ---- prologue: load tile 0 into regs, stage bi only
    float4 cur[2][4];
    #pragma unroll
    for (int it = 0; it < 2; ++it) {
        int r = r0 + it * 8;
        const float4* p = reinterpret_cast<const float4*>(
            res + (tile0 * BM + r) * (NSTREAMS * DIM)) + d4;
        cur[it][0] = p[0];
        cur[it][1] = p[64];
        cur[it][2] = p[128];
        cur[it][3] = p[192];
        float4 bi;
        bi.x = hp0 * cur[it][0].x + hp1 * cur[it][1].x + hp2 * cur[it][2].x + hp3 * cur[it][3].x;
        bi.y = hp0 * cur[it][0].y + hp1 * cur[it][1].y + hp2 * cur[it][2].y + hp3 * cur[it][3].y;
        bi.z = hp0 * cur[it][0].z + hp1 * cur[it][1].z + hp2 * cur[it][2].z + hp3 * cur[it][3].z;
        bi.w = hp0 * cur[it][0].w + hp1 * cur[it][1].w + hp2 * cur[it][2].w + hp3 * cur[it][3].w;
        *reinterpret_cast<int2*>(&bi_lds[r][d4 * 4]) = f2bf4(bi);
    }
    barrier_lgkm();

    for (int ti = 0; ti < TILES; ++ti) {
        // ---- GEMM (R7-proven 8-wave indexing): wave w owns d in [32w,32w+32)
        f32x4 acc[2] = {f32x4{0.f, 0.f, 0.f, 0.f}, f32x4{0.f, 0.f, 0.f, 0.f}};
        for (int k0 = 0; k0 < DIM; k0 += 32) {
            short8 a = *reinterpret_cast<const short8*>(&bi_lds[lr][k0 + lk * 8]);
            #pragma unroll
            for (int nt = 0; nt < 2; ++nt) {
                int dcol = w * 32 + nt * 16 + lr;
                short8 b;
                if (USE_WSW) {
                    b = *reinterpret_cast<const short8*>(wbf + dcol * DIM + k0 + lk * 8);
                } else {
                    const float4* wp = reinterpret_cast<const float4*>(Wb + dcol * DIM + k0 + lk * 8);
                    float4 wa = wp[0];
                    float4 wb2 = wp[1];
                    b[0] = f2bf(wa.x); b[1] = f2bf(wa.y); b[2] = f2bf(wa.z); b[3] = f2bf(wa.w);
                    b[4] = f2bf(wb2.x); b[5] = f2bf(wb2.y); b[6] = f2bf(wb2.z); b[7] = f2bf(wb2.w);
                }
                acc[nt] = __builtin_amdgcn_mfma_f32_16x16x32_bf16(a, b, acc[nt], 0, 0, 0);
            }
        }

        // ---- issue next tile's loads NOW: after all W loads (in-order vmcnt
        // retirement -> MFMAs never wait on these), before scatter + barrier +
        // epilogue, so ~full tile of work covers the HBM latency. The lgkm-only
        // barriers below do NOT drain vmcnt, so these stay in flight.
        float4 nx[2][4];
        const bool more = (ti + 1 < TILES);
        if (more) {
            #pragma unroll
            for (int it = 0; it < 2; ++it) {
                int r = r0 + it * 8;
                const float4* p = reinterpret_cast<const float4*>(
                    res + ((tile0 + ti + 1) * BM + r) * (NSTREAMS * DIM)) + d4;
                nx[it][0] = p[0];
                nx[it][1] = p[64];
                nx[it][2] = p[128];
                nx[it][3] = p[192];
            }
        }

        // ---- bo redistribution write (proven C/D layout), f32 — no cvt
        #pragma unroll
        for (int nt = 0; nt < 2; ++nt) {
            int d = w * 32 + nt * 16 + lr;
            #pragma unroll
            for (int j = 0; j < 4; ++j)
                bo_lds[lk * 4 + j][d] = acc[nt][j];
        }
        barrier_lgkm();   // (mid) bo visible; GEMM's bi reads drained

        // ---- epilogue: bo from LDS (f32) + residuals from f32 regs
        #pragma unroll
        for (int it = 0; it < 2; ++it) {
            int r = r0 + it * 8;
            float4 bo = *reinterpret_cast<const float4*>(&bo_lds[r][d4 * 4]);
            float* obase = out + (((tile0 + ti) * BM + r) * 4) * DIM + d4 * 4;
            #pragma unroll
            for (int tt = 0; tt < 4; ++tt) {
                float4 o;
                o.x = hq[tt] * bo.x + hres[0][tt] * cur[it][0].x + hres[1][tt] * cur[it][1].x
                    + hres[2][tt] * cur[it][2].x + hres[3][tt] * cur[it][3].x;
                o.y = hq[tt] * bo.y + hres[0][tt] * cur[it][0].y + hres[1][tt] * cur[it][1].y
                    + hres[2][tt] * cur[it][2].y + hres[3][tt] * cur[it][3].y;
                o.z = hq[tt] * bo.z + hres[0][tt] * cur[it][0].z + hres[1][tt] * cur[it][1].z
                    + hres[2][tt] * cur[it][2].z + hres[3][tt] * cur[it][3].z;
                o.w = hq[tt] * bo.w + hres[0][tt] * cur[it][0].w + hres[1][tt] * cur[it][1].w
                    + hres[2][tt] * cur[it][2].w + hres[3][tt] * cur[it][3].w;
                *reinterpret_cast<float4*>(obase + tt * DIM) = o;
            }
        }

        // ---- stage next bi into bi_lds (GEMM reads drained at mid barrier);
        //      vmcnt wait on nx happens here, after the whole epilogue.
        if (more) {
            #pragma unroll
            for (int it = 0; it < 2; ++it) {
                int r = r0 + it * 8;
                float4 bi;
                bi.x = hp0 * nx[it][0].x + hp1 * nx[it][1].x + hp2 * nx[it][2].x + hp3 * nx[it][3].x;
                bi.y = hp0 * nx[it][0].y + hp1 * nx[it][1].y + hp2 * nx[it][2].y + hp3 * nx[it][3].y;
                bi.z = hp0 * nx[it][0].z + hp1 * nx[it][1].z + hp2 * nx[it][2].z + hp3 * nx[it][3].z;
                bi.w = hp0 * nx[it][0].w + hp1 * nx[it][1].w + hp2 * nx[it][2].w + hp3 * nx[it][3].w;
                *reinterpret_cast<int2*>(&bi_lds[r][d4 * 4]) = f2bf4(bi);
                #pragma unroll
                for (int s = 0; s < 4; ++s)
                    cur[it][s] = nx[it][s];
            }
        }
        barrier_lgkm();   // (end) bi staging visible for next iter
    }
}

extern "C" void kernel_launch(void* const* d_in, const int* in_sizes, int n_in,
                              void* d_out, int out_size, void* d_ws, size_t ws_size,
                              hipStream_t stream) {
    const float* res     = (const float*)d_in[0];
    const float* hres_l  = (const float*)d_in[1];
    const float* hpre_l  = (const float*)d_in[2];
    const float* hpost_l = (const float*)d_in[3];
    const float* Wb      = (const float*)d_in[4];
    float* out = (float*)d_out;

    const int Btot = in_sizes[0] / (NSTREAMS * DIM);   // 65536
    const int grid = Btot / (BM * TILES);              // 512

    const size_t W_OFF = 256;
    const size_t need_h = 24 * sizeof(float);
    const size_t need_w = W_OFF + (size_t)DIM * DIM * sizeof(short);
    const bool has_h = ws_size >= need_h;
    const bool has_w = ws_size >= need_w;

    float* ws_h = (float*)d_ws;
    short* ws_w = (short*)((char*)d_ws + W_OFF);

    if (has_w) {
        prep_wh_kernel<<<(DIM * DIM / 4) / 256, 256, 0, stream>>>(
            Wb, ws_w, hres_l, hpre_l, hpost_l, ws_h);
        fused_kernel<true><<<grid, NTHREADS, 0, stream>>>(
            res, Wb, ws_w, ws_h, hres_l, hpre_l, hpost_l, out);
    } else if (has_h) {
        prep_h_kernel<<<1, 64, 0, stream>>>(hres_l, hpre_l, hpost_l, ws_h);
        fused_kernel<false><<<grid, NTHREADS, 0, stream>>>(
            res, Wb, nullptr, ws_h, hres_l, hpre_l, hpost_l, out);
    } else {
        fused_kernel<false><<<grid, NTHREADS, 0, stream>>>(
            res, Wb, nullptr, nullptr, hres_l, hpre_l, hpost_l, out);
    }
}

// Round 2
// 129.678 us; speedup vs baseline: 1.5445x; 1.5445x over previous
//
#include <hip/hip_runtime.h>

#define NSTREAMS 4
#define DIM 256
#define BM 16
#define NTHREADS 512
#define TILES 8

typedef __attribute__((ext_vector_type(8))) short short8;
typedef __attribute__((ext_vector_type(4))) float f32x4;

// f32 -> bf16 round-to-nearest-even (scalar, bit-twiddle)
static __device__ __forceinline__ short f2bf(float x) {
    union { float f; unsigned int u; } c; c.f = x;
    unsigned int u = c.u;
    unsigned int lsb = (u >> 16) & 1u;
    u += 0x7fffu + lsb;
    return (short)(u >> 16);
}
// f32x4 -> packed bf16x4 via HW v_cvt_pk_bf16_f32 (RNE, bit-identical to f2bf)
static __device__ __forceinline__ int2 f2bf4(float4 v) {
    unsigned int lo, hi;
    asm("v_cvt_pk_bf16_f32 %0, %1, %2" : "=v"(lo) : "v"(v.x), "v"(v.y));
    asm("v_cvt_pk_bf16_f32 %0, %1, %2" : "=v"(hi) : "v"(v.z), "v"(v.w));
    int2 r; r.x = (int)lo; r.y = (int)hi;
    return r;
}

// Block-uniform float -> SGPR (all lanes hold the same value).
static __device__ __forceinline__ float rfl(float x) {
    int i = __builtin_amdgcn_readfirstlane(__builtin_bit_cast(int, x));
    return __builtin_bit_cast(float, i);
}

// Block barrier that drains LDS ops only — does NOT drain vmcnt, so global
// loads issued before it stay in flight across the barrier (T4 discipline).
// All global loads in this kernel land in registers, so LDS visibility
// (lgkmcnt) is the only cross-wave hazard at these barriers.
static __device__ __forceinline__ void barrier_lgkm() {
    asm volatile("s_waitcnt lgkmcnt(0)\n\ts_barrier" ::: "memory");
}

// Sinkhorn (4x4, 10 iters, tau=0.05) + two softmaxes.
// h_out[0..15]=h_res (row-major s,t), [16..19]=h_pre, [20..23]=h_post
static __device__ void compute_h(const float* __restrict__ hres_l,
                                 const float* __restrict__ hpre_l,
                                 const float* __restrict__ hpost_l,
                                 float* h_out) {
    const float inv_tau = 1.0f / 0.05f;
    float z[4][4];
    for (int i = 0; i < 4; ++i)
        for (int j = 0; j < 4; ++j)
            z[i][j] = hres_l[i * 4 + j] * inv_tau;
    float u[4] = {0.f, 0.f, 0.f, 0.f};
    float v[4] = {0.f, 0.f, 0.f, 0.f};
    const float logm = -logf(4.0f);
    for (int it = 0; it < 10; ++it) {
        for (int i = 0; i < 4; ++i) {
            float m = -1e30f;
            for (int j = 0; j < 4; ++j) m = fmaxf(m, z[i][j] + v[j]);
            float ss = 0.f;
            for (int j = 0; j < 4; ++j) ss += expf(z[i][j] + v[j] - m);
            u[i] = logm - (m + logf(ss));
        }
        for (int j = 0; j < 4; ++j) {
            float m = -1e30f;
            for (int i = 0; i < 4; ++i) m = fmaxf(m, z[i][j] + u[i]);
            float ss = 0.f;
            for (int i = 0; i < 4; ++i) ss += expf(z[i][j] + u[i] - m);
            v[j] = logm - (m + logf(ss));
        }
    }
    for (int i = 0; i < 4; ++i)
        for (int j = 0; j < 4; ++j)
            h_out[i * 4 + j] = expf(z[i][j] + u[i] + v[j]) * 4.0f;
    {
        float m = fmaxf(fmaxf(hpre_l[0], hpre_l[1]), fmaxf(hpre_l[2], hpre_l[3]));
        float e0 = expf(hpre_l[0] - m), e1 = expf(hpre_l[1] - m);
        float e2 = expf(hpre_l[2] - m), e3 = expf(hpre_l[3] - m);
        float ss = e0 + e1 + e2 + e3;
        h_out[16] = e0 / ss; h_out[17] = e1 / ss; h_out[18] = e2 / ss; h_out[19] = e3 / ss;
    }
    {
        float m = fmaxf(fmaxf(hpost_l[0], hpost_l[1]), fmaxf(hpost_l[2], hpost_l[3]));
        float e0 = expf(hpost_l[0] - m), e1 = expf(hpost_l[1] - m);
        float e2 = expf(hpost_l[2] - m), e3 = expf(hpost_l[3] - m);
        float ss = e0 + e1 + e2 + e3;
        h_out[20] = e0 / ss; h_out[21] = e1 / ss; h_out[22] = e2 / ss; h_out[23] = e3 / ss;
    }
}

__global__ void prep_h_kernel(const float* __restrict__ hres_l,
                              const float* __restrict__ hpre_l,
                              const float* __restrict__ hpost_l,
                              float* __restrict__ ws) {
    if (threadIdx.x == 0) compute_h(hres_l, hpre_l, hpost_l, ws);
}

// Convert W to bf16 into ws (RNE) + compute h in block 0 (disjoint ws region).
__global__ __launch_bounds__(256) void prep_wh_kernel(const float* __restrict__ Wb,
                                                      short* __restrict__ wbf,
                                                      const float* __restrict__ hres_l,
                                                      const float* __restrict__ hpre_l,
                                                      const float* __restrict__ hpost_l,
                                                      float* __restrict__ ws_h) {
    int idx = blockIdx.x * 256 + threadIdx.x;   // 16384 float4 tasks
    float4 v = reinterpret_cast<const float4*>(Wb)[idx];
    reinterpret_cast<int2*>(wbf)[idx] = f2bf4(v);
    if (blockIdx.x == 0 && threadIdx.x == 0)
        compute_h(hres_l, hpre_l, hpost_l, ws_h);
}

template <bool USE_WSW>
__global__ __launch_bounds__(NTHREADS, 2) void fused_kernel(
    const float* __restrict__ res,
    const float* __restrict__ Wb,
    const short* __restrict__ wbf,    // bf16 W in ws (when USE_WSW)
    const float* __restrict__ hptr,   // 24 floats in ws, or nullptr
    const float* __restrict__ hres_l,
    const float* __restrict__ hpre_l,
    const float* __restrict__ hpost_l,
    float* __restrict__ out)
{
    // res kept in f32 registers across a tile (no res_lds round-trip).
    // bo_lds is f32 (no bf16 round-trip); +4 pad -> 2-way conflicts (free).
    __shared__ __align__(16) short bi_lds[BM][DIM + 8];   // 8.25 KB
    __shared__ __align__(16) float bo_lds[BM][DIM + 4];   // 16.6 KB
    __shared__ float h_sh[24];

    const int t  = threadIdx.x;
    const int d4 = t & 63;
    const int r0 = t >> 6;    // 0..7; this thread owns rows r0 and r0+8
    const int w  = t >> 6;    // GEMM wave id 0..7
    const int l  = t & 63;
    const int lr = l & 15;    // A row / B col within 16-tile
    const int lk = l >> 4;    // k-block 0..3

    if (hptr) {
        if (t < 24) h_sh[t] = hptr[t];
    } else if (t == 0) {
        compute_h(hres_l, hpre_l, hpost_l, h_sh);
    }
    barrier_lgkm();

    // h coefficients are block-uniform: pin them to SGPRs (frees ~24 VGPRs).
    const float hp0 = rfl(h_sh[16]), hp1 = rfl(h_sh[17]);
    const float hp2 = rfl(h_sh[18]), hp3 = rfl(h_sh[19]);
    float hres[4][4];
    #pragma unroll
    for (int s = 0; s < 4; ++s)
        #pragma unroll
        for (int tt = 0; tt < 4; ++tt)
            hres[s][tt] = rfl(h_sh[s * 4 + tt]);
    float hq[4] = {rfl(h_sh[20]), rfl(h_sh[21]), rfl(h_sh[22]), rfl(h_sh[23])};

    const long tile0 = (long)blockIdx.x * TILES;

    // ---- prologue: load tile 0 into regs, stage bi only
    float4 cur[2][4];
    #pragma unroll
    for (int it = 0; it < 2; ++it) {
        int r = r0 + it * 8;
        const float4* p = reinterpret_cast<const float4*>(
            res + (tile0 * BM + r) * (NSTREAMS * DIM)) + d4;
        cur[it][0] = p[0];
        cur[it][1] = p[64];
        cur[it][2] = p[128];
        cur[it][3] = p[192];
        float4 bi;
        bi.x = hp0 * cur[it][0].x + hp1 * cur[it][1].x + hp2 * cur[it][2].x + hp3 * cur[it][3].x;
        bi.y = hp0 * cur[it][0].y + hp1 * cur[it][1].y + hp2 * cur[it][2].y + hp3 * cur[it][3].y;
        bi.z = hp0 * cur[it][0].z + hp1 * cur[it][1].z + hp2 * cur[it][2].z + hp3 * cur[it][3].z;
        bi.w = hp0 * cur[it][0].w + hp1 * cur[it][1].w + hp2 * cur[it][2].w + hp3 * cur[it][3].w;
        *reinterpret_cast<int2*>(&bi_lds[r][d4 * 4]) = f2bf4(bi);
    }
    barrier_lgkm();

    for (int ti = 0; ti < TILES; ++ti) {
        // ---- GEMM (R7-proven 8-wave indexing): wave w owns d in [32w,32w+32)
        f32x4 acc[2] = {f32x4{0.f, 0.f, 0.f, 0.f}, f32x4{0.f, 0.f, 0.f, 0.f}};
        for (int k0 = 0; k0 < DIM; k0 += 32) {
            short8 a = *reinterpret_cast<const short8*>(&bi_lds[lr][k0 + lk * 8]);
            #pragma unroll
            for (int nt = 0; nt < 2; ++nt) {
                int dcol = w * 32 + nt * 16 + lr;
                short8 b;
                if (USE_WSW) {
                    b = *reinterpret_cast<const short8*>(wbf + dcol * DIM + k0 + lk * 8);
                } else {
                    const float4* wp = reinterpret_cast<const float4*>(Wb + dcol * DIM + k0 + lk * 8);
                    float4 wa = wp[0];
                    float4 wb2 = wp[1];
                    b[0] = f2bf(wa.x); b[1] = f2bf(wa.y); b[2] = f2bf(wa.z); b[3] = f2bf(wa.w);
                    b[4] = f2bf(wb2.x); b[5] = f2bf(wb2.y); b[6] = f2bf(wb2.z); b[7] = f2bf(wb2.w);
                }
                acc[nt] = __builtin_amdgcn_mfma_f32_16x16x32_bf16(a, b, acc[nt], 0, 0, 0);
            }
        }

        // ---- issue next tile's loads NOW: after all W loads (in-order vmcnt
        // retirement -> MFMAs never wait on these), before scatter + barrier +
        // epilogue, so ~full tile of work covers the HBM latency. The lgkm-only
        // barriers below do NOT drain vmcnt, so these stay in flight.
        float4 nx[2][4];
        const bool more = (ti + 1 < TILES);
        if (more) {
            #pragma unroll
            for (int it = 0; it < 2; ++it) {
                int r = r0 + it * 8;
                const float4* p = reinterpret_cast<const float4*>(
                    res + ((tile0 + ti + 1) * BM + r) * (NSTREAMS * DIM)) + d4;
                nx[it][0] = p[0];
                nx[it][1] = p[64];
                nx[it][2] = p[128];
                nx[it][3] = p[192];
            }
        }

        // ---- bo redistribution write (proven C/D layout), f32 — no cvt
        #pragma unroll
        for (int nt = 0; nt < 2; ++nt) {
            int d = w * 32 + nt * 16 + lr;
            #pragma unroll
            for (int j = 0; j < 4; ++j)
                bo_lds[lk * 4 + j][d] = acc[nt][j];
        }
        barrier_lgkm();   // (mid) bo visible; GEMM's bi reads drained

        // ---- epilogue: bo from LDS (f32) + residuals from f32 regs
        #pragma unroll
        for (int it = 0; it < 2; ++it) {
            int r = r0 + it * 8;
            float4 bo = *reinterpret_cast<const float4*>(&bo_lds[r][d4 * 4]);
            float* obase = out + (((tile0 + ti) * BM + r) * 4) * DIM + d4 * 4;
            #pragma unroll
            for (int tt = 0; tt < 4; ++tt) {
                float4 o;
                o.x = hq[tt] * bo.x + hres[0][tt] * cur[it][0].x + hres[1][tt] * cur[it][1].x
                    + hres[2][tt] * cur[it][2].x + hres[3][tt] * cur[it][3].x;
                o.y = hq[tt] * bo.y + hres[0][tt] * cur[it][0].y + hres[1][tt] * cur[it][1].y
                    + hres[2][tt] * cur[it][2].y + hres[3][tt] * cur[it][3].y;
                o.z = hq[tt] * bo.z + hres[0][tt] * cur[it][0].z + hres[1][tt] * cur[it][1].z
                    + hres[2][tt] * cur[it][2].z + hres[3][tt] * cur[it][3].z;
                o.w = hq[tt] * bo.w + hres[0][tt] * cur[it][0].w + hres[1][tt] * cur[it][1].w
                    + hres[2][tt] * cur[it][2].w + hres[3][tt] * cur[it][3].w;
                *reinterpret_cast<float4*>(obase + tt * DIM) = o;
            }
        }

        // ---- stage next bi into bi_lds (GEMM reads drained at mid barrier);
        //      vmcnt wait on nx happens here, after the whole epilogue.
        if (more) {
            #pragma unroll
            for (int it = 0; it < 2; ++it) {
                int r = r0 + it * 8;
                float4 bi;
                bi.x = hp0 * nx[it][0].x + hp1 * nx[it][1].x + hp2 * nx[it][2].x + hp3 * nx[it][3].x;
                bi.y = hp0 * nx[it][0].y + hp1 * nx[it][1].y + hp2 * nx[it][2].y + hp3 * nx[it][3].y;
                bi.z = hp0 * nx[it][0].z + hp1 * nx[it][1].z + hp2 * nx[it][2].z + hp3 * nx[it][3].z;
                bi.w = hp0 * nx[it][0].w + hp1 * nx[it][1].w + hp2 * nx[it][2].w + hp3 * nx[it][3].w;
                *reinterpret_cast<int2*>(&bi_lds[r][d4 * 4]) = f2bf4(bi);
                #pragma unroll
                for (int s = 0; s < 4; ++s)
                    cur[it][s] = nx[it][s];
            }
        }
        barrier_lgkm();   // (end) bi staging visible for next iter
    }
}

extern "C" void kernel_launch(void* const* d_in, const int* in_sizes, int n_in,
                              void* d_out, int out_size, void* d_ws, size_t ws_size,
                              hipStream_t stream) {
    const float* res     = (const float*)d_in[0];
    const float* hres_l  = (const float*)d_in[1];
    const float* hpre_l  = (const float*)d_in[2];
    const float* hpost_l = (const float*)d_in[3];
    const float* Wb      = (const float*)d_in[4];
    float* out = (float*)d_out;

    const int Btot = in_sizes[0] / (NSTREAMS * DIM);   // 65536
    const int grid = Btot / (BM * TILES);              // 512

    const size_t W_OFF = 256;
    const size_t need_h = 24 * sizeof(float);
    const size_t need_w = W_OFF + (size_t)DIM * DIM * sizeof(short);
    const bool has_h = ws_size >= need_h;
    const bool has_w = ws_size >= need_w;

    float* ws_h = (float*)d_ws;
    short* ws_w = (short*)((char*)d_ws + W_OFF);

    if (has_w) {
        prep_wh_kernel<<<(DIM * DIM / 4) / 256, 256, 0, stream>>>(
            Wb, ws_w, hres_l, hpre_l, hpost_l, ws_h);
        fused_kernel<true><<<grid, NTHREADS, 0, stream>>>(
            res, Wb, ws_w, ws_h, hres_l, hpre_l, hpost_l, out);
    } else if (has_h) {
        prep_h_kernel<<<1, 64, 0, stream>>>(hres_l, hpre_l, hpost_l, ws_h);
        fused_kernel<false><<<grid, NTHREADS, 0, stream>>>(
            res, Wb, nullptr, ws_h, hres_l, hpre_l, hpost_l, out);
    } else {
        fused_kernel<false><<<grid, NTHREADS, 0, stream>>>(
            res, Wb, nullptr, nullptr, hres_l, hpre_l, hpost_l, out);
    }
}

// Round 3
// 128.703 us; speedup vs baseline: 1.5562x; 1.0076x over previous
//
#include <hip/hip_runtime.h>

#define NSTREAMS 4
#define DIM 256
#define BM 16
#define NTHREADS 1024
#define TILES 16

typedef __attribute__((ext_vector_type(8))) short short8;
typedef __attribute__((ext_vector_type(4))) float f32x4;

// f32 -> bf16 round-to-nearest-even (scalar, bit-twiddle)
static __device__ __forceinline__ short f2bf(float x) {
    union { float f; unsigned int u; } c; c.f = x;
    unsigned int u = c.u;
    unsigned int lsb = (u >> 16) & 1u;
    u += 0x7fffu + lsb;
    return (short)(u >> 16);
}
// f32x4 -> packed bf16x4 via HW v_cvt_pk_bf16_f32 (RNE, bit-identical to f2bf)
static __device__ __forceinline__ int2 f2bf4(float4 v) {
    unsigned int lo, hi;
    asm("v_cvt_pk_bf16_f32 %0, %1, %2" : "=v"(lo) : "v"(v.x), "v"(v.y));
    asm("v_cvt_pk_bf16_f32 %0, %1, %2" : "=v"(hi) : "v"(v.z), "v"(v.w));
    int2 r; r.x = (int)lo; r.y = (int)hi;
    return r;
}

// Block-uniform float -> SGPR (all lanes hold the same value).
static __device__ __forceinline__ float rfl(float x) {
    int i = __builtin_amdgcn_readfirstlane(__builtin_bit_cast(int, x));
    return __builtin_bit_cast(float, i);
}

// Block barrier that drains LDS ops only — does NOT drain vmcnt, so global
// loads issued before it stay in flight across the barrier (T4 discipline).
// All global loads in this kernel land in registers, so LDS visibility
// (lgkmcnt) is the only cross-wave hazard at these barriers.
static __device__ __forceinline__ void barrier_lgkm() {
    asm volatile("s_waitcnt lgkmcnt(0)\n\ts_barrier" ::: "memory");
}

// Sinkhorn (4x4, 10 iters, tau=0.05) + two softmaxes.
// h_out[0..15]=h_res (row-major s,t), [16..19]=h_pre, [20..23]=h_post
static __device__ void compute_h(const float* __restrict__ hres_l,
                                 const float* __restrict__ hpre_l,
                                 const float* __restrict__ hpost_l,
                                 float* h_out) {
    const float inv_tau = 1.0f / 0.05f;
    float z[4][4];
    for (int i = 0; i < 4; ++i)
        for (int j = 0; j < 4; ++j)
            z[i][j] = hres_l[i * 4 + j] * inv_tau;
    float u[4] = {0.f, 0.f, 0.f, 0.f};
    float v[4] = {0.f, 0.f, 0.f, 0.f};
    const float logm = -logf(4.0f);
    for (int it = 0; it < 10; ++it) {
        for (int i = 0; i < 4; ++i) {
            float m = -1e30f;
            for (int j = 0; j < 4; ++j) m = fmaxf(m, z[i][j] + v[j]);
            float ss = 0.f;
            for (int j = 0; j < 4; ++j) ss += expf(z[i][j] + v[j] - m);
            u[i] = logm - (m + logf(ss));
        }
        for (int j = 0; j < 4; ++j) {
            float m = -1e30f;
            for (int i = 0; i < 4; ++i) m = fmaxf(m, z[i][j] + u[i]);
            float ss = 0.f;
            for (int i = 0; i < 4; ++i) ss += expf(z[i][j] + u[i] - m);
            v[j] = logm - (m + logf(ss));
        }
    }
    for (int i = 0; i < 4; ++i)
        for (int j = 0; j < 4; ++j)
            h_out[i * 4 + j] = expf(z[i][j] + u[i] + v[j]) * 4.0f;
    {
        float m = fmaxf(fmaxf(hpre_l[0], hpre_l[1]), fmaxf(hpre_l[2], hpre_l[3]));
        float e0 = expf(hpre_l[0] - m), e1 = expf(hpre_l[1] - m);
        float e2 = expf(hpre_l[2] - m), e3 = expf(hpre_l[3] - m);
        float ss = e0 + e1 + e2 + e3;
        h_out[16] = e0 / ss; h_out[17] = e1 / ss; h_out[18] = e2 / ss; h_out[19] = e3 / ss;
    }
    {
        float m = fmaxf(fmaxf(hpost_l[0], hpost_l[1]), fmaxf(hpost_l[2], hpost_l[3]));
        float e0 = expf(hpost_l[0] - m), e1 = expf(hpost_l[1] - m);
        float e2 = expf(hpost_l[2] - m), e3 = expf(hpost_l[3] - m);
        float ss = e0 + e1 + e2 + e3;
        h_out[20] = e0 / ss; h_out[21] = e1 / ss; h_out[22] = e2 / ss; h_out[23] = e3 / ss;
    }
}

__global__ void prep_h_kernel(const float* __restrict__ hres_l,
                              const float* __restrict__ hpre_l,
                              const float* __restrict__ hpost_l,
                              float* __restrict__ ws) {
    if (threadIdx.x == 0) compute_h(hres_l, hpre_l, hpost_l, ws);
}

// Convert W to bf16 into ws (RNE) + compute h in block 0 (disjoint ws region).
__global__ __launch_bounds__(256) void prep_wh_kernel(const float* __restrict__ Wb,
                                                      short* __restrict__ wbf,
                                                      const float* __restrict__ hres_l,
                                                      const float* __restrict__ hpre_l,
                                                      const float* __restrict__ hpost_l,
                                                      float* __restrict__ ws_h) {
    int idx = blockIdx.x * 256 + threadIdx.x;   // 16384 float4 tasks
    float4 v = reinterpret_cast<const float4*>(Wb)[idx];
    reinterpret_cast<int2*>(wbf)[idx] = f2bf4(v);
    if (blockIdx.x == 0 && threadIdx.x == 0)
        compute_h(hres_l, hpre_l, hpost_l, ws_h);
}

template <bool USE_WSW>
__global__ __launch_bounds__(NTHREADS, 1) void fused_kernel(
    const float* __restrict__ res,
    const float* __restrict__ Wb,
    const short* __restrict__ wbf,    // bf16 W in ws (when USE_WSW)
    const float* __restrict__ hptr,   // 24 floats in ws, or nullptr
    const float* __restrict__ hres_l,
    const float* __restrict__ hpre_l,
    const float* __restrict__ hpost_l,
    float* __restrict__ out)
{
    // W staged in LDS (XOR-swizzled rows): GEMM becomes LDS-only (lgkm), so
    // next-tile HBM loads can be issued at the TOP of each tile with zero
    // vmcnt coupling — reads stay in flight across the whole tile.
    __shared__ __align__(16) short W_lds[DIM * DIM];      // 128 KB
    __shared__ __align__(16) short bi_lds[BM][DIM + 8];   // 8.25 KB
    __shared__ __align__(16) float bo_lds[BM][DIM + 4];   // 16.25 KB
    __shared__ float h_sh[24];

    const int t  = threadIdx.x;
    const int d4 = t & 63;
    const int r0 = t >> 6;    // 0..15: the row this thread owns
    const int w  = t >> 6;    // wave id 0..15
    const int l  = t & 63;
    const int lr = l & 15;    // A row / B col within 16-tile
    const int lk = l >> 4;    // k-block 0..3

    // ---- prologue: issue tile-0 res loads FIRST (longest latency)
    const long tile0 = (long)blockIdx.x * TILES;
    float4 cur[4];
    {
        const float4* p = reinterpret_cast<const float4*>(
            res + (tile0 * BM + r0) * (NSTREAMS * DIM)) + d4;
        cur[0] = p[0];
        cur[1] = p[64];
        cur[2] = p[128];
        cur[3] = p[192];
    }

    // ---- stage W into LDS, XOR-swizzled: byte dst = (row<<9)|(koff^((row&7)<<4))
    // Read side uses the same XOR -> 16-lane column reads become 2-way (free).
    #pragma unroll
    for (int i = 0; i < 8; ++i) {
        int c = t * 8 + i;            // 16B-chunk id, 0..8191 (8192*16B = 128KB)
        int row = c >> 5;             // W row (= output col d); 512B per row
        int koff = (c & 31) * 16;     // byte offset within row
        int dst = (row << 9) | (koff ^ ((row & 7) << 4));
        int4 wv;
        if (USE_WSW) {
            wv = reinterpret_cast<const int4*>(wbf)[c];
        } else {
            const float4* wp = reinterpret_cast<const float4*>(Wb) + c * 2;
            float4 wa = wp[0], wb2 = wp[1];
            int2 loq = f2bf4(wa), hiq = f2bf4(wb2);
            wv.x = loq.x; wv.y = loq.y; wv.z = hiq.x; wv.w = hiq.y;
        }
        *reinterpret_cast<int4*>(reinterpret_cast<char*>(W_lds) + dst) = wv;
    }

    if (hptr) {
        if (t < 24) h_sh[t] = hptr[t];
    } else if (t == 0) {
        compute_h(hres_l, hpre_l, hpost_l, h_sh);
    }
    barrier_lgkm();

    // h coefficients are block-uniform: pin them to SGPRs.
    const float hp0 = rfl(h_sh[16]), hp1 = rfl(h_sh[17]);
    const float hp2 = rfl(h_sh[18]), hp3 = rfl(h_sh[19]);
    float hres[4][4];
    #pragma unroll
    for (int s = 0; s < 4; ++s)
        #pragma unroll
        for (int tt = 0; tt < 4; ++tt)
            hres[s][tt] = rfl(h_sh[s * 4 + tt]);
    float hq[4] = {rfl(h_sh[20]), rfl(h_sh[21]), rfl(h_sh[22]), rfl(h_sh[23])};

    // ---- stage tile-0 bi
    {
        float4 bi;
        bi.x = hp0 * cur[0].x + hp1 * cur[1].x + hp2 * cur[2].x + hp3 * cur[3].x;
        bi.y = hp0 * cur[0].y + hp1 * cur[1].y + hp2 * cur[2].y + hp3 * cur[3].y;
        bi.z = hp0 * cur[0].z + hp1 * cur[1].z + hp2 * cur[2].z + hp3 * cur[3].z;
        bi.w = hp0 * cur[0].w + hp1 * cur[1].w + hp2 * cur[2].w + hp3 * cur[3].w;
        *reinterpret_cast<int2*>(&bi_lds[r0][d4 * 4]) = f2bf4(bi);
    }
    barrier_lgkm();

    // GEMM addressing (constant over tiles): wave w owns d in [16w, 16w+16)
    const int dcol = w * 16 + lr;
    const char* wbase = reinterpret_cast<const char*>(W_lds) + (dcol << 9);
    const int dswz = (dcol & 7) << 4;

    for (int ti = 0; ti < TILES; ++ti) {
        const bool more = (ti + 1 < TILES);

        // ---- issue next tile's HBM loads at the TOP: no vmcnt consumer until
        // the stage phase at the bottom, and the GEMM below is LDS-only, so
        // these fly across the entire tile (GEMM + 2 barriers + epilogue).
        float4 nx[4];
        if (more) {
            const float4* p = reinterpret_cast<const float4*>(
                res + ((tile0 + ti + 1) * BM + r0) * (NSTREAMS * DIM)) + d4;
            nx[0] = p[0];
            nx[1] = p[64];
            nx[2] = p[128];
            nx[3] = p[192];
        }
        __builtin_amdgcn_sched_barrier(0);   // pin: nx issued before the GEMM

        // ---- GEMM: LDS-only operands (bi + swizzled W)
        f32x4 acc = {0.f, 0.f, 0.f, 0.f};
        #pragma unroll
        for (int k0 = 0; k0 < DIM; k0 += 32) {
            short8 a = *reinterpret_cast<const short8*>(&bi_lds[lr][k0 + lk * 8]);
            short8 b = *reinterpret_cast<const short8*>(
                wbase + ((k0 * 2 + lk * 16) ^ dswz));
            acc = __builtin_amdgcn_mfma_f32_16x16x32_bf16(a, b, acc, 0, 0, 0);
        }

        // ---- bo redistribution write (proven C/D layout), f32
        #pragma unroll
        for (int j = 0; j < 4; ++j)
            bo_lds[lk * 4 + j][dcol] = acc[j];

        barrier_lgkm();   // (mid) bo visible; GEMM's bi/W LDS reads drained

        // ---- epilogue: bo from LDS (f32) + residuals from f32 regs
        {
            float4 bo = *reinterpret_cast<const float4*>(&bo_lds[r0][d4 * 4]);
            float* obase = out + (((tile0 + ti) * BM + r0) * 4) * DIM + d4 * 4;
            #pragma unroll
            for (int tt = 0; tt < 4; ++tt) {
                float4 o;
                o.x = hq[tt] * bo.x + hres[0][tt] * cur[0].x + hres[1][tt] * cur[1].x
                    + hres[2][tt] * cur[2].x + hres[3][tt] * cur[3].x;
                o.y = hq[tt] * bo.y + hres[0][tt] * cur[0].y + hres[1][tt] * cur[1].y
                    + hres[2][tt] * cur[2].y + hres[3][tt] * cur[3].y;
                o.z = hq[tt] * bo.z + hres[0][tt] * cur[0].z + hres[1][tt] * cur[1].z
                    + hres[2][tt] * cur[2].z + hres[3][tt] * cur[3].z;
                o.w = hq[tt] * bo.w + hres[0][tt] * cur[0].w + hres[1][tt] * cur[1].w
                    + hres[2][tt] * cur[2].w + hres[3][tt] * cur[3].w;
                *reinterpret_cast<float4*>(obase + tt * DIM) = o;
            }
        }

        // ---- stage next bi (vmcnt wait on nx lands here, a full tile after
        // issue); bi_lds write is safe: all GEMM reads drained at mid barrier.
        if (more) {
            float4 bi;
            bi.x = hp0 * nx[0].x + hp1 * nx[1].x + hp2 * nx[2].x + hp3 * nx[3].x;
            bi.y = hp0 * nx[0].y + hp1 * nx[1].y + hp2 * nx[2].y + hp3 * nx[3].y;
            bi.z = hp0 * nx[0].z + hp1 * nx[1].z + hp2 * nx[2].z + hp3 * nx[3].z;
            bi.w = hp0 * nx[0].w + hp1 * nx[1].w + hp2 * nx[2].w + hp3 * nx[3].w;
            *reinterpret_cast<int2*>(&bi_lds[r0][d4 * 4]) = f2bf4(bi);
            #pragma unroll
            for (int s = 0; s < 4; ++s)
                cur[s] = nx[s];
        }
        barrier_lgkm();   // (end) bi staging visible for next iter
    }
}

extern "C" void kernel_launch(void* const* d_in, const int* in_sizes, int n_in,
                              void* d_out, int out_size, void* d_ws, size_t ws_size,
                              hipStream_t stream) {
    const float* res     = (const float*)d_in[0];
    const float* hres_l  = (const float*)d_in[1];
    const float* hpre_l  = (const float*)d_in[2];
    const float* hpost_l = (const float*)d_in[3];
    const float* Wb      = (const float*)d_in[4];
    float* out = (float*)d_out;

    const int Btot = in_sizes[0] / (NSTREAMS * DIM);   // 65536
    const int grid = Btot / (BM * TILES);              // 256 = 1 block/CU

    const size_t W_OFF = 256;
    const size_t need_h = 24 * sizeof(float);
    const size_t need_w = W_OFF + (size_t)DIM * DIM * sizeof(short);
    const bool has_h = ws_size >= need_h;
    const bool has_w = ws_size >= need_w;

    float* ws_h = (float*)d_ws;
    short* ws_w = (short*)((char*)d_ws + W_OFF);

    if (has_w) {
        prep_wh_kernel<<<(DIM * DIM / 4) / 256, 256, 0, stream>>>(
            Wb, ws_w, hres_l, hpre_l, hpost_l, ws_h);
        fused_kernel<true><<<grid, NTHREADS, 0, stream>>>(
            res, Wb, ws_w, ws_h, hres_l, hpre_l, hpost_l, out);
    } else if (has_h) {
        prep_h_kernel<<<1, 64, 0, stream>>>(hres_l, hpre_l, hpost_l, ws_h);
        fused_kernel<false><<<grid, NTHREADS, 0, stream>>>(
            res, Wb, nullptr, ws_h, hres_l, hpre_l, hpost_l, out);
    } else {
        fused_kernel<false><<<grid, NTHREADS, 0, stream>>>(
            res, Wb, nullptr, nullptr, hres_l, hpre_l, hpost_l, out);
    }
}